// Round 3
// baseline (22908.690 us; speedup 1.0000x reference)
//
#include <hip/hip_runtime.h>
#include <hip/hip_cooperative_groups.h>
#include <cstddef>
#include <cstdint>

namespace cg = cooperative_groups;

#define B 32
#define TENC 2048
#define TDEC 128
#define NCH 8     // attn chunks per batch: 32 b x 8 ch = 256 blocks
#define TCH 256   // t per chunk (4 waves x 64)

typedef unsigned short ushort_t;
typedef __attribute__((ext_vector_type(8))) short short8;
typedef __attribute__((ext_vector_type(4))) float floatx4;

// ---------------- helpers ----------------
__device__ __forceinline__ uint16_t f2bf(float x) {
    uint32_t u = __float_as_uint(x);
    u += 0x7fffu + ((u >> 16) & 1u);  // RNE
    return (uint16_t)(u >> 16);
}
__device__ __forceinline__ float bf2f(ushort_t u) {
    return __uint_as_float(((uint32_t)u) << 16);
}
__device__ __forceinline__ void unpack8(uint4 v, float* f) {
    f[0] = __uint_as_float(v.x << 16); f[1] = __uint_as_float(v.x & 0xffff0000u);
    f[2] = __uint_as_float(v.y << 16); f[3] = __uint_as_float(v.y & 0xffff0000u);
    f[4] = __uint_as_float(v.z << 16); f[5] = __uint_as_float(v.z & 0xffff0000u);
    f[6] = __uint_as_float(v.w << 16); f[7] = __uint_as_float(v.w & 0xffff0000u);
}
__device__ __forceinline__ float fast_tanh(float x) {
    float e = __expf(2.f * x);
    return 1.f - 2.f * __builtin_amdgcn_rcpf(e + 1.f);
}
__device__ __forceinline__ float fast_sig(float x) {
    return __builtin_amdgcn_rcpf(1.f + __expf(-x));
}

// ---------------- f32 -> bf16 bulk convert (count = grid*2048) ----------------
__global__ void cvt_kernel(const float* __restrict__ in, ushort_t* __restrict__ out) {
    int i = blockIdx.x * 256 + threadIdx.x;  // 8 elements each
    const float4* ip = (const float4*)in;
    float4 a = ip[2 * i], b = ip[2 * i + 1];
    uint4 o;
    o.x = (uint32_t)f2bf(a.x) | ((uint32_t)f2bf(a.y) << 16);
    o.y = (uint32_t)f2bf(a.z) | ((uint32_t)f2bf(a.w) << 16);
    o.z = (uint32_t)f2bf(b.x) | ((uint32_t)f2bf(b.y) << 16);
    o.w = (uint32_t)f2bf(b.z) | ((uint32_t)f2bf(b.w) << 16);
    ((uint4*)out)[i] = o;
}

// ---------------- transpose (+ optional cvt): out[c*R+r] = in[r*C+c] ----------------
__global__ void tr_cvt_bf16_kernel(const float* __restrict__ in, ushort_t* __restrict__ out,
                                   int R, int C) {
    __shared__ float tile[32][33];
    int r0 = blockIdx.y * 32, c0 = blockIdx.x * 32;
    int tx = threadIdx.x & 31, ty = threadIdx.x >> 5;
#pragma unroll
    for (int i = 0; i < 4; i++) {
        int r = ty + i * 8;
        tile[r][tx] = in[(size_t)(r0 + r) * C + c0 + tx];
    }
    __syncthreads();
#pragma unroll
    for (int i = 0; i < 4; i++) {
        int rr = ty + i * 8;
        out[(size_t)(c0 + rr) * R + r0 + tx] = f2bf(tile[tx][rr]);
    }
}
__global__ void tr_f32_kernel(const float* __restrict__ in, float* __restrict__ out,
                              int R, int C) {
    __shared__ float tile[32][33];
    int r0 = blockIdx.y * 32, c0 = blockIdx.x * 32;
    int tx = threadIdx.x & 31, ty = threadIdx.x >> 5;
#pragma unroll
    for (int i = 0; i < 4; i++) {
        int r = ty + i * 8;
        tile[r][tx] = in[(size_t)(r0 + r) * C + c0 + tx];
    }
    __syncthreads();
#pragma unroll
    for (int i = 0; i < 4; i++) {
        int rr = ty + i * 8;
        out[(size_t)(c0 + rr) * R + r0 + tx] = tile[tx][rr];
    }
}

// ---------------- bz[g] = bias[g] + b3 @ Wk[:,g] ----------------
__global__ void bz_kernel(const float* __restrict__ b3, const float* __restrict__ Wk,
                          const float* __restrict__ bias, float* __restrict__ bz) {
    int g = blockIdx.x * 256 + threadIdx.x;
    float s = bias[g];
#pragma unroll 8
    for (int u = 0; u < 512; u++) s += b3[u] * Wk[(size_t)u * 2048 + g];
    bz[g] = s;
}

// ---------------- MFMA bf16 GEMM: C[M,N] = A[M,512] x Bt[N,512]^T ----------------
// block 256 = 4 waves (2x2), 64x64 tile; wave does 32x32 via 2x2 16x16x32 frags.
template <int BF16OUT>
__global__ void mfma_gemm_kernel(const ushort_t* __restrict__ A, const ushort_t* __restrict__ Bt,
                                 void* __restrict__ C, int M, int N) {
    int tid = threadIdx.x, wave = tid >> 6, lane = tid & 63;
    int wy = wave & 1, wx = wave >> 1;
    int m0 = blockIdx.y * 64 + wy * 32;
    int n0 = blockIdx.x * 64 + wx * 32;
    int lr = lane & 15, quad = lane >> 4;
    floatx4 a00 = {0.f, 0.f, 0.f, 0.f}, a01 = a00, a10 = a00, a11 = a00;
    const short8* Ap0 = (const short8*)(A + (size_t)(m0 + lr) * 512 + quad * 8);
    const short8* Ap1 = (const short8*)(A + (size_t)(m0 + 16 + lr) * 512 + quad * 8);
    const short8* Bp0 = (const short8*)(Bt + (size_t)(n0 + lr) * 512 + quad * 8);
    const short8* Bp1 = (const short8*)(Bt + (size_t)(n0 + 16 + lr) * 512 + quad * 8);
#pragma unroll 4
    for (int k = 0; k < 16; k++) {
        short8 av0 = Ap0[k * 4], av1 = Ap1[k * 4];
        short8 bv0 = Bp0[k * 4], bv1 = Bp1[k * 4];
        a00 = __builtin_amdgcn_mfma_f32_16x16x32_bf16(av0, bv0, a00, 0, 0, 0);
        a01 = __builtin_amdgcn_mfma_f32_16x16x32_bf16(av0, bv1, a01, 0, 0, 0);
        a10 = __builtin_amdgcn_mfma_f32_16x16x32_bf16(av1, bv0, a10, 0, 0, 0);
        a11 = __builtin_amdgcn_mfma_f32_16x16x32_bf16(av1, bv1, a11, 0, 0, 0);
    }
    int rb = quad * 4;
    if (BF16OUT) {
        ushort_t* Cp = (ushort_t*)C;
#pragma unroll
        for (int r = 0; r < 4; r++) {
            Cp[(size_t)(m0 + rb + r) * N + n0 + lr] = f2bf(a00[r]);
            Cp[(size_t)(m0 + rb + r) * N + n0 + 16 + lr] = f2bf(a01[r]);
            Cp[(size_t)(m0 + 16 + rb + r) * N + n0 + lr] = f2bf(a10[r]);
            Cp[(size_t)(m0 + 16 + rb + r) * N + n0 + 16 + lr] = f2bf(a11[r]);
        }
    } else {
        float* Cp = (float*)C;
#pragma unroll
        for (int r = 0; r < 4; r++) {
            Cp[(size_t)(m0 + rb + r) * N + n0 + lr] = a00[r];
            Cp[(size_t)(m0 + rb + r) * N + n0 + 16 + lr] = a01[r];
            Cp[(size_t)(m0 + 16 + rb + r) * N + n0 + lr] = a10[r];
            Cp[(size_t)(m0 + 16 + rb + r) * N + n0 + 16 + lr] = a11[r];
        }
    }
}

// =================== persistent cooperative decode kernel ===================
// 256 blocks x 256 threads, 1 block/CU. 4 grid syncs per step.
__global__ __launch_bounds__(256, 1) void step_kernel(
    const ushort_t* __restrict__ xW1h, const ushort_t* __restrict__ ench,
    const ushort_t* __restrict__ Zxh, const float* __restrict__ bz,
    const float* __restrict__ W2t, const float* __restrict__ Wrt,
    const float* __restrict__ Wazt, const float* __restrict__ Vv,
    const float* __restrict__ b2,
    float* __restrict__ h, float* __restrict__ c, float* __restrict__ hW2,
    float* __restrict__ zbuf, float* __restrict__ pm, float* __restrict__ pl,
    float* __restrict__ pacc, float* __restrict__ Xa, float* __restrict__ out) {
    cg::grid_group grid = cg::this_grid();
    int bk = blockIdx.x, tid = threadIdx.x;
    int wave = tid >> 6, lane = tid & 63;
    __shared__ float smem[21560];

    for (int t = 0; t < TDEC; ++t) {
        // ---- S2: hW2 = h@W2t + b2 ; zbuf = h@Wrt + Zx[b,t] + bz ----
        // cols n0..n0+9 of the concatenated [W2t | Wrt] (2560 cols / 256 blocks)
        {
            for (int idx = tid; idx < 16384; idx += 256)
                smem[(idx >> 9) * 513 + (idx & 511)] = h[idx];
            int n0 = bk * 10;
            for (int idx = tid; idx < 5120; idx += 256) {
                int cc = idx >> 9, d = idx & 511;
                int n = n0 + cc;
                const float* src = (n < 512) ? (W2t + (size_t)n * 512)
                                             : (Wrt + (size_t)(n - 512) * 512);
                smem[16416 + cc * 513 + d] = src[d];
            }
            __syncthreads();
            int q = tid & 3;
#pragma unroll
            for (int r = 0; r < 5; ++r) {
                int o = r * 64 + (tid >> 2);
                int cc = o >> 5, b = o & 31;
                const float* hrow = smem + b * 513;
                const float* wrow = smem + 16416 + cc * 513;
                float acc = 0.f;
#pragma unroll 8
                for (int i = 0; i < 128; ++i) {
                    int d = q + 4 * i;
                    acc += hrow[d] * wrow[d];
                }
                acc += __shfl_xor(acc, 1, 64);
                acc += __shfl_xor(acc, 2, 64);
                if (q == 0) {
                    int n = n0 + cc;
                    if (n < 512) {
                        hW2[b * 512 + n] = acc + b2[n];
                    } else {
                        int g = n - 512;
                        float zx = bf2f(Zxh[((size_t)(b * 128 + t)) * 2048 + g]);
                        zbuf[b * 2048 + g] = acc + zx + bz[g];
                    }
                }
            }
        }
        grid.sync();
        // ---- S3: flash attention partials over one T-chunk ----
        {
            int b = bk >> 3, ch = bk & 7;
            float hs[8], vs[8];
            {
                const float4* hp = (const float4*)(hW2 + b * 512 + lane * 8);
                float4 h0 = hp[0], h1 = hp[1];
                hs[0] = h0.x; hs[1] = h0.y; hs[2] = h0.z; hs[3] = h0.w;
                hs[4] = h1.x; hs[5] = h1.y; hs[6] = h1.z; hs[7] = h1.w;
                const float4* vp = (const float4*)(Vv + lane * 8);
                float4 v0 = vp[0], v1 = vp[1];
                vs[0] = v0.x; vs[1] = v0.y; vs[2] = v0.z; vs[3] = v0.w;
                vs[4] = v1.x; vs[5] = v1.y; vs[6] = v1.z; vs[7] = v1.w;
            }
            int t0 = ch * TCH + wave * 64;
            const uint4* xr = (const uint4*)xW1h + ((size_t)b * TENC + t0) * 64 + lane;
            const uint4* er = (const uint4*)ench + ((size_t)b * TENC + t0) * 64 + lane;
            float m = -INFINITY, l = 0.f;
            float acc[8] = {0.f, 0.f, 0.f, 0.f, 0.f, 0.f, 0.f, 0.f};
#pragma unroll 2
            for (int tt = 0; tt < 64; ++tt) {
                uint4 xv = xr[(size_t)tt * 64];
                uint4 ev = er[(size_t)tt * 64];
                float xf[8], ef[8];
                unpack8(xv, xf);
                float s = 0.f;
#pragma unroll
                for (int j = 0; j < 8; j++) s += fast_tanh(xf[j] + hs[j]) * vs[j];
#pragma unroll
                for (int off = 32; off >= 1; off >>= 1) s += __shfl_xor(s, off, 64);
                float mn = fmaxf(m, s);
                float sc = __expf(m - mn);
                float p = __expf(s - mn);
                l = l * sc + p;
                unpack8(ev, ef);
#pragma unroll
                for (int j = 0; j < 8; j++) acc[j] = acc[j] * sc + p * ef[j];
                m = mn;
            }
            float* smv = smem;
            float* slv = smem + 8;
            float* sacc = smem + 16;
            if (lane == 0) { smv[wave] = m; slv[wave] = l; }
            __syncthreads();
            float bmx = fmaxf(fmaxf(smv[0], smv[1]), fmaxf(smv[2], smv[3]));
            float f = __expf(m - bmx);
#pragma unroll
            for (int j = 0; j < 8; j++) sacc[wave * 512 + lane * 8 + j] = acc[j] * f;
            __syncthreads();
            float s0 = sacc[tid] + sacc[512 + tid] + sacc[1024 + tid] + sacc[1536 + tid];
            float s1 = sacc[tid + 256] + sacc[512 + tid + 256] + sacc[1024 + tid + 256] +
                       sacc[1536 + tid + 256];
            size_t po = ((size_t)(b * NCH + ch)) * 512;
            pacc[po + tid] = s0;
            pacc[po + tid + 256] = s1;
            if (tid == 0) {
                pm[b * NCH + ch] = bmx;
                pl[b * NCH + ch] = slv[0] * __expf(smv[0] - bmx) + slv[1] * __expf(smv[1] - bmx) +
                                   slv[2] * __expf(smv[2] - bmx) + slv[3] * __expf(smv[3] - bmx);
            }
        }
        grid.sync();
        // ---- S4: combine chunk partials -> Xa (b x dseg partition) ----
        {
            int b = bk >> 3, ds0 = (bk & 7) * 64;
            if (tid < 64) {
                float mg = -1e30f;
#pragma unroll
                for (int i = 0; i < NCH; i++) mg = fmaxf(mg, pm[b * NCH + i]);
                float w[NCH];
                float L = 0.f;
#pragma unroll
                for (int i = 0; i < NCH; i++) {
                    w[i] = __expf(pm[b * NCH + i] - mg);
                    L += pl[b * NCH + i] * w[i];
                }
                float inv = __builtin_amdgcn_rcpf(L);
                int d = ds0 + tid;
                float s = 0.f;
#pragma unroll
                for (int i = 0; i < NCH; i++)
                    s += w[i] * pacc[((size_t)(b * NCH + i)) * 512 + d];
                Xa[b * 512 + d] = s * inv;
            }
        }
        grid.sync();
        // ---- S5: z += Xa@Waz (via Wazt rows) + gates + state update ----
        // block owns u's {2bk, 2bk+1} x 4 gate quadrants = 8 z-cols x all 32 b
        {
            for (int idx = tid; idx < 16384; idx += 256)
                smem[(idx >> 9) * 513 + (idx & 511)] = Xa[idx];
            int u0 = bk * 2;
            for (int idx = tid; idx < 4096; idx += 256) {
                int rw = idx >> 9, d = idx & 511;
                int g = (rw >> 1) * 512 + u0 + (rw & 1);
                smem[16416 + rw * 513 + d] = Wazt[(size_t)g * 512 + d];
            }
            __syncthreads();
            int col = tid >> 5, b = tid & 31;
            const float* xrow = smem + b * 513;
            const float* wrow = smem + 16416 + col * 513;
            float acc = 0.f;
#pragma unroll 8
            for (int d = 0; d < 512; ++d) acc += xrow[d] * wrow[d];
            int g = (col >> 1) * 512 + u0 + (col & 1);
            smem[20800 + col * 32 + b] = acc + zbuf[b * 2048 + g];
            __syncthreads();
            if (tid < 64) {
                int bb = tid >> 1, uo = tid & 1;
                int u = u0 + uo;
                float zi = smem[20800 + (0 + uo) * 32 + bb];
                float zf = smem[20800 + (2 + uo) * 32 + bb];
                float zg = smem[20800 + (4 + uo) * 32 + bb];
                float zo = smem[20800 + (6 + uo) * 32 + bb];
                float ig = fast_sig(zi);
                float fg = fast_sig(zf);
                float gg = fast_tanh(zg);
                float og = fast_sig(zo);
                int idx = bb * 512 + u;
                float cn = fg * c[idx] + ig * gg;
                float hn = og * fast_tanh(cn);
                c[idx] = cn;
                h[idx] = hn;
                out[((size_t)bb * TDEC + t) * 512 + u] = hn;
            }
        }
        grid.sync();
    }
}

extern "C" void kernel_launch(void* const* d_in, const int* in_sizes, int n_in,
                              void* d_out, int out_size, void* d_ws, size_t ws_size,
                              hipStream_t stream) {
    const float* enc = (const float*)d_in[0];
    const float* dec = (const float*)d_in[1];
    const float* W1 = (const float*)d_in[2];
    const float* W2 = (const float*)d_in[3];
    const float* b2 = (const float*)d_in[4];
    const float* V = (const float*)d_in[5];
    const float* W3 = (const float*)d_in[6];
    const float* b3 = (const float*)d_in[7];
    const float* Wk = (const float*)d_in[8];
    const float* Wr = (const float*)d_in[9];
    const float* bias = (const float*)d_in[10];
    float* out = (float*)d_out;

    char* ws = (char*)d_ws;
    size_t o = 0;
    auto alloc = [&](size_t bytes) {
        void* p = ws + o;
        o += (bytes + 255) & ~(size_t)255;
        return p;
    };
    ushort_t* xW1h = (ushort_t*)alloc(67108864);        // [65536][512] bf16
    ushort_t* ench = (ushort_t*)alloc(67108864);        // [65536][512] bf16
    ushort_t* Zxh = (ushort_t*)alloc(16777216);         // [4096][2048] bf16
    ushort_t* dech = (ushort_t*)alloc(4194304);         // [4096][512] bf16
    ushort_t* T1h = (ushort_t*)alloc(4194304);          // [4096][512] bf16
    ushort_t* W1t = (ushort_t*)alloc(524288);           // [512][512] bf16 (W1^T)
    ushort_t* W3h = (ushort_t*)alloc(1048576);          // [1024][512] bf16 (W3 as-is)
    ushort_t* W3at = (ushort_t*)alloc(524288);          // [512][512] bf16 (upper W3^T)
    ushort_t* Wkt = (ushort_t*)alloc(2097152);          // [2048][512] bf16 (Wk^T)
    float* W2t = (float*)alloc(1048576);                // [512][512] f32 (W2^T)
    float* Wrt = (float*)alloc(4194304);                // [2048][512] f32 (Wr^T)
    float* Wazt = (float*)alloc(4194304);               // [2048][512] f32 ((W3b@Wk)^T)
    float* bz = (float*)alloc(8192);                    // [2048]
    float* h = (float*)alloc(65536);                    // [32][512]
    float* c = (float*)alloc(65536);                    // [32][512] (contiguous after h)
    float* hW2 = (float*)alloc(65536);
    float* Xa = (float*)alloc(65536);
    float* zbuf = (float*)alloc(262144);                // [32][2048]
    float* pm = (float*)alloc(1024);
    float* pl = (float*)alloc(1024);
    float* pacc = (float*)alloc(524288);                // [32][8][512]

    hipMemsetAsync(h, 0, 131072, stream);  // h and c

    // one-time converts / transposes
    cvt_kernel<<<16384, 256, 0, stream>>>(enc, ench);
    cvt_kernel<<<1024, 256, 0, stream>>>(dec, dech);
    cvt_kernel<<<256, 256, 0, stream>>>(W3, W3h);
    tr_cvt_bf16_kernel<<<dim3(16, 16), 256, 0, stream>>>(W1, W1t, 512, 512);
    tr_cvt_bf16_kernel<<<dim3(16, 16), 256, 0, stream>>>(W3, W3at, 512, 512);
    tr_cvt_bf16_kernel<<<dim3(64, 16), 256, 0, stream>>>(Wk, Wkt, 512, 2048);
    tr_f32_kernel<<<dim3(16, 16), 256, 0, stream>>>(W2, W2t, 512, 512);
    tr_f32_kernel<<<dim3(64, 16), 256, 0, stream>>>(Wr, Wrt, 512, 2048);
    bz_kernel<<<8, 256, 0, stream>>>(b3, Wk, bias, bz);
    // one-time GEMMs (bf16 MFMA)
    mfma_gemm_kernel<1><<<dim3(8, 1024), 256, 0, stream>>>(ench, W1t, xW1h, 65536, 512);
    mfma_gemm_kernel<1><<<dim3(8, 64), 256, 0, stream>>>(dech, W3at, T1h, 4096, 512);
    mfma_gemm_kernel<1><<<dim3(32, 64), 256, 0, stream>>>(T1h, Wkt, Zxh, 4096, 2048);
    mfma_gemm_kernel<0><<<dim3(8, 32), 256, 0, stream>>>(Wkt, W3h + 512 * 512, Wazt, 2048, 512);

    // persistent decode loop (one cooperative dispatch, 4 grid syncs/step)
    void* args[] = {&xW1h, &ench, &Zxh, &bz, &W2t, &Wrt, &Wazt, &V, &b2,
                    &h, &c, &hW2, &zbuf, &pm, &pl, &pacc, &Xa, &out};
    hipLaunchCooperativeKernel((void*)step_kernel, dim3(256), dim3(256), args, 0, stream);
}

// Round 4
// 21817.592 us; speedup vs baseline: 1.0500x; 1.0500x over previous
//
#include <hip/hip_runtime.h>
#include <hip/hip_cooperative_groups.h>
#include <cstddef>
#include <cstdint>

namespace cg = cooperative_groups;

#define B 32
#define TENC 2048
#define TDEC 128
#define NCH 8     // attn chunks per batch: 32 b x 8 ch = 256 blocks
#define TCH 256   // t per chunk (8 waves x 32)

typedef unsigned short ushort_t;
typedef __attribute__((ext_vector_type(8))) short short8;
typedef __attribute__((ext_vector_type(4))) float floatx4;

// ---------------- helpers ----------------
__device__ __forceinline__ uint16_t f2bf(float x) {
    uint32_t u = __float_as_uint(x);
    u += 0x7fffu + ((u >> 16) & 1u);  // RNE
    return (uint16_t)(u >> 16);
}
__device__ __forceinline__ void unpack8(uint4 v, float* f) {
    f[0] = __uint_as_float(v.x << 16); f[1] = __uint_as_float(v.x & 0xffff0000u);
    f[2] = __uint_as_float(v.y << 16); f[3] = __uint_as_float(v.y & 0xffff0000u);
    f[4] = __uint_as_float(v.z << 16); f[5] = __uint_as_float(v.z & 0xffff0000u);
    f[6] = __uint_as_float(v.w << 16); f[7] = __uint_as_float(v.w & 0xffff0000u);
}
__device__ __forceinline__ float fast_tanh(float x) {
    float e = __expf(2.f * x);
    return 1.f - 2.f * __builtin_amdgcn_rcpf(e + 1.f);
}
__device__ __forceinline__ float fast_sig(float x) {
    return __builtin_amdgcn_rcpf(1.f + __expf(-x));
}

// ---------------- f32 -> bf16 bulk convert (count = grid*2048) ----------------
__global__ void cvt_kernel(const float* __restrict__ in, ushort_t* __restrict__ out) {
    int i = blockIdx.x * 256 + threadIdx.x;  // 8 elements each
    const float4* ip = (const float4*)in;
    float4 a = ip[2 * i], b = ip[2 * i + 1];
    uint4 o;
    o.x = (uint32_t)f2bf(a.x) | ((uint32_t)f2bf(a.y) << 16);
    o.y = (uint32_t)f2bf(a.z) | ((uint32_t)f2bf(a.w) << 16);
    o.z = (uint32_t)f2bf(b.x) | ((uint32_t)f2bf(b.y) << 16);
    o.w = (uint32_t)f2bf(b.z) | ((uint32_t)f2bf(b.w) << 16);
    ((uint4*)out)[i] = o;
}

// ---------------- transpose (+ optional cvt): out[c*R+r] = in[r*C+c] ----------------
__global__ void tr_cvt_bf16_kernel(const float* __restrict__ in, ushort_t* __restrict__ out,
                                   int R, int C) {
    __shared__ float tile[32][33];
    int r0 = blockIdx.y * 32, c0 = blockIdx.x * 32;
    int tx = threadIdx.x & 31, ty = threadIdx.x >> 5;
#pragma unroll
    for (int i = 0; i < 4; i++) {
        int r = ty + i * 8;
        tile[r][tx] = in[(size_t)(r0 + r) * C + c0 + tx];
    }
    __syncthreads();
#pragma unroll
    for (int i = 0; i < 4; i++) {
        int rr = ty + i * 8;
        out[(size_t)(c0 + rr) * R + r0 + tx] = f2bf(tile[tx][rr]);
    }
}
__global__ void tr_f32_kernel(const float* __restrict__ in, float* __restrict__ out,
                              int R, int C) {
    __shared__ float tile[32][33];
    int r0 = blockIdx.y * 32, c0 = blockIdx.x * 32;
    int tx = threadIdx.x & 31, ty = threadIdx.x >> 5;
#pragma unroll
    for (int i = 0; i < 4; i++) {
        int r = ty + i * 8;
        tile[r][tx] = in[(size_t)(r0 + r) * C + c0 + tx];
    }
    __syncthreads();
#pragma unroll
    for (int i = 0; i < 4; i++) {
        int rr = ty + i * 8;
        out[(size_t)(c0 + rr) * R + r0 + tx] = tile[tx][rr];
    }
}

// ---------------- bz[g] = bias[g] + b3 @ Wk[:,g] ----------------
__global__ void bz_kernel(const float* __restrict__ b3, const float* __restrict__ Wk,
                          const float* __restrict__ bias, float* __restrict__ bz) {
    int g = blockIdx.x * 256 + threadIdx.x;
    float s = bias[g];
#pragma unroll 8
    for (int u = 0; u < 512; u++) s += b3[u] * Wk[(size_t)u * 2048 + g];
    bz[g] = s;
}

// -------- one-time: xW1 = enc @ W1, fp32 math (single bf16 store-rounding) --------
__global__ void gemm_xw1_kernel(const float* __restrict__ A, const float* __restrict__ Bm,
                                ushort_t* __restrict__ C) {
    __shared__ float As[16][68];
    __shared__ float Bs[16][68];
    int bm = blockIdx.y * 64, bn = blockIdx.x * 64;
    int tx = threadIdx.x & 15, ty = threadIdx.x >> 4;
    float acc[4][4] = {};
    for (int k0 = 0; k0 < 512; k0 += 16) {
#pragma unroll
        for (int i = 0; i < 4; i++) {
            int idx = threadIdx.x + 256 * i;
            int r = idx >> 4, kk = idx & 15;
            As[kk][r] = A[(size_t)(bm + r) * 512 + k0 + kk];
            int cc = idx & 63, kb = idx >> 6;
            Bs[kb][cc] = Bm[(size_t)(k0 + kb) * 512 + bn + cc];
        }
        __syncthreads();
#pragma unroll
        for (int kk = 0; kk < 16; kk++) {
            float4 av = *(const float4*)&As[kk][ty * 4];
            float4 bv = *(const float4*)&Bs[kk][tx * 4];
            float a[4] = {av.x, av.y, av.z, av.w};
            float b[4] = {bv.x, bv.y, bv.z, bv.w};
#pragma unroll
            for (int i = 0; i < 4; i++)
#pragma unroll
                for (int j = 0; j < 4; j++) acc[i][j] += a[i] * b[j];
        }
        __syncthreads();
    }
#pragma unroll
    for (int i = 0; i < 4; i++) {
        uint2 o;
        o.x = (uint32_t)f2bf(acc[i][0]) | ((uint32_t)f2bf(acc[i][1]) << 16);
        o.y = (uint32_t)f2bf(acc[i][2]) | ((uint32_t)f2bf(acc[i][3]) << 16);
        *(uint2*)(C + (size_t)(bm + ty * 4 + i) * 512 + bn + tx * 4) = o;
    }
}

// ---------------- MFMA bf16 GEMM: C[M,N] = A[M,512] x Bt[N,512]^T ----------------
template <int BF16OUT>
__global__ void mfma_gemm_kernel(const ushort_t* __restrict__ A, const ushort_t* __restrict__ Bt,
                                 void* __restrict__ C, int M, int N) {
    int tid = threadIdx.x, wave = tid >> 6, lane = tid & 63;
    int wy = wave & 1, wx = wave >> 1;
    int m0 = blockIdx.y * 64 + wy * 32;
    int n0 = blockIdx.x * 64 + wx * 32;
    int lr = lane & 15, quad = lane >> 4;
    floatx4 a00 = {0.f, 0.f, 0.f, 0.f}, a01 = a00, a10 = a00, a11 = a00;
    const short8* Ap0 = (const short8*)(A + (size_t)(m0 + lr) * 512 + quad * 8);
    const short8* Ap1 = (const short8*)(A + (size_t)(m0 + 16 + lr) * 512 + quad * 8);
    const short8* Bp0 = (const short8*)(Bt + (size_t)(n0 + lr) * 512 + quad * 8);
    const short8* Bp1 = (const short8*)(Bt + (size_t)(n0 + 16 + lr) * 512 + quad * 8);
#pragma unroll 4
    for (int k = 0; k < 16; k++) {
        short8 av0 = Ap0[k * 4], av1 = Ap1[k * 4];
        short8 bv0 = Bp0[k * 4], bv1 = Bp1[k * 4];
        a00 = __builtin_amdgcn_mfma_f32_16x16x32_bf16(av0, bv0, a00, 0, 0, 0);
        a01 = __builtin_amdgcn_mfma_f32_16x16x32_bf16(av0, bv1, a01, 0, 0, 0);
        a10 = __builtin_amdgcn_mfma_f32_16x16x32_bf16(av1, bv0, a10, 0, 0, 0);
        a11 = __builtin_amdgcn_mfma_f32_16x16x32_bf16(av1, bv1, a11, 0, 0, 0);
    }
    int rb = quad * 4;
    if (BF16OUT) {
        ushort_t* Cp = (ushort_t*)C;
#pragma unroll
        for (int r = 0; r < 4; r++) {
            Cp[(size_t)(m0 + rb + r) * N + n0 + lr] = f2bf(a00[r]);
            Cp[(size_t)(m0 + rb + r) * N + n0 + 16 + lr] = f2bf(a01[r]);
            Cp[(size_t)(m0 + 16 + rb + r) * N + n0 + lr] = f2bf(a10[r]);
            Cp[(size_t)(m0 + 16 + rb + r) * N + n0 + 16 + lr] = f2bf(a11[r]);
        }
    } else {
        float* Cp = (float*)C;
#pragma unroll
        for (int r = 0; r < 4; r++) {
            Cp[(size_t)(m0 + rb + r) * N + n0 + lr] = a00[r];
            Cp[(size_t)(m0 + rb + r) * N + n0 + 16 + lr] = a01[r];
            Cp[(size_t)(m0 + 16 + rb + r) * N + n0 + lr] = a10[r];
            Cp[(size_t)(m0 + 16 + rb + r) * N + n0 + 16 + lr] = a11[r];
        }
    }
}

// =================== persistent cooperative decode kernel ===================
// 256 blocks x 512 threads (8 waves/CU). 4 grid syncs per step.
__global__ __launch_bounds__(512, 2) void step_kernel(
    const ushort_t* __restrict__ xW1h, const ushort_t* __restrict__ ench,
    const float* __restrict__ Zxf, const float* __restrict__ bz,
    const float* __restrict__ W2t, const float* __restrict__ Wrt,
    const float* __restrict__ Wazt, const float* __restrict__ Vv,
    const float* __restrict__ b2,
    float* __restrict__ h, float* __restrict__ c, float* __restrict__ hW2,
    float* __restrict__ zbuf, float* __restrict__ pl,
    float* __restrict__ pacc, float* __restrict__ Xa, float* __restrict__ out) {
    cg::grid_group grid = cg::this_grid();
    int bk = blockIdx.x, tid = threadIdx.x;
    int wave = tid >> 6, lane = tid & 63;
    __shared__ float smem[21560];

    // attention-phase per-lane constants (V is loop-invariant)
    float vs[8];
    {
        const float4* vp = (const float4*)(Vv + lane * 8);
        float4 v0 = vp[0], v1 = vp[1];
        vs[0] = v0.x; vs[1] = v0.y; vs[2] = v0.z; vs[3] = v0.w;
        vs[4] = v1.x; vs[5] = v1.y; vs[6] = v1.z; vs[7] = v1.w;
    }

    for (int t = 0; t < TDEC; ++t) {
        // ---- S2: hW2 = h@W2t + b2 ; zbuf = h@Wrt + Zx[b,t] + bz ----
        // this block owns cols n0..n0+9 of concat [W2t | Wrt] (2560 cols / 256 blocks)
        {
            for (int idx = tid; idx < 16384; idx += 512)
                smem[(idx >> 9) * 513 + (idx & 511)] = h[idx];
            int n0 = bk * 10;
            for (int idx = tid; idx < 5120; idx += 512) {
                int cc = idx >> 9, d = idx & 511;
                int n = n0 + cc;
                const float* src = (n < 512) ? (W2t + (size_t)n * 512)
                                             : (Wrt + (size_t)(n - 512) * 512);
                smem[16416 + cc * 513 + d] = src[d];
            }
            __syncthreads();
            int q = tid & 3, slot = tid >> 2;
#pragma unroll
            for (int r = 0; r < 3; ++r) {
                int o = r * 128 + slot;
                bool valid = (o < 320);
                int cc = o >> 5, b = o & 31;
                if (cc > 9) cc = 9;
                const float* hrow = smem + b * 513;
                const float* wrow = smem + 16416 + cc * 513;
                float acc = 0.f;
#pragma unroll 8
                for (int i = 0; i < 128; ++i) {
                    int d = q + 4 * i;
                    acc += hrow[d] * wrow[d];
                }
                acc += __shfl_xor(acc, 1, 64);
                acc += __shfl_xor(acc, 2, 64);
                if (q == 0 && valid) {
                    int n = n0 + cc;
                    if (n < 512) {
                        hW2[b * 512 + n] = acc + b2[n];
                    } else {
                        int g = n - 512;
                        zbuf[b * 2048 + g] =
                            acc + Zxf[((size_t)(b * 128 + t)) * 2048 + g] + bz[g];
                    }
                }
            }
        }
        grid.sync();
        // ---- S3: fixed-base softmax attention partials (depth-4 prefetch) ----
        {
            int b = bk >> 3, ch = bk & 7;
            float hs[8];
            {
                const float4* hp = (const float4*)(hW2 + b * 512 + lane * 8);
                float4 h0 = hp[0], h1 = hp[1];
                hs[0] = h0.x; hs[1] = h0.y; hs[2] = h0.z; hs[3] = h0.w;
                hs[4] = h1.x; hs[5] = h1.y; hs[6] = h1.z; hs[7] = h1.w;
            }
            int t0 = ch * TCH + wave * 32;
            const uint4* xr = (const uint4*)xW1h + ((size_t)b * TENC + t0) * 64 + lane;
            const uint4* er = (const uint4*)ench + ((size_t)b * TENC + t0) * 64 + lane;
            float l = 0.f;
            float acc[8] = {0.f, 0.f, 0.f, 0.f, 0.f, 0.f, 0.f, 0.f};

            auto body = [&](uint4 xv, uint4 ev) {
                float xf[8], ef[8];
                unpack8(xv, xf);
                float s = 0.f;
#pragma unroll
                for (int j = 0; j < 8; j++) s += fast_tanh(xf[j] + hs[j]) * vs[j];
#pragma unroll
                for (int off = 32; off >= 1; off >>= 1) s += __shfl_xor(s, off, 64);
                float p = __expf(s);  // |s| <= ~21 -> safe in fp32 without max
                l += p;
                unpack8(ev, ef);
#pragma unroll
                for (int j = 0; j < 8; j++) acc[j] += p * ef[j];
            };

            uint4 xb[4], eb[4];
#pragma unroll
            for (int i = 0; i < 4; i++) {
                xb[i] = xr[(size_t)i * 64];
                eb[i] = er[(size_t)i * 64];
            }
#pragma unroll 4
            for (int tt = 0; tt < 28; ++tt) {
                int sl = tt & 3;
                uint4 xv = xb[sl], ev = eb[sl];
                xb[sl] = xr[(size_t)(tt + 4) * 64];
                eb[sl] = er[(size_t)(tt + 4) * 64];
                body(xv, ev);
            }
#pragma unroll
            for (int tt = 28; tt < 32; ++tt) body(xb[tt & 3], eb[tt & 3]);

            // block combine: plain sums across 8 waves
            float* slv = smem;            // [8]
            float* sacc = smem + 16;      // [8][512]
            if (lane == 0) slv[wave] = l;
            float4* sa = (float4*)(sacc + wave * 512 + lane * 8);
            sa[0] = make_float4(acc[0], acc[1], acc[2], acc[3]);
            sa[1] = make_float4(acc[4], acc[5], acc[6], acc[7]);
            __syncthreads();
            float sd = 0.f;
#pragma unroll
            for (int w = 0; w < 8; w++) sd += sacc[w * 512 + tid];
            size_t po = ((size_t)(b * NCH + ch)) * 512;
            pacc[po + tid] = sd;
            if (tid == 0) {
                float ls = 0.f;
#pragma unroll
                for (int w = 0; w < 8; w++) ls += slv[w];
                pl[b * NCH + ch] = ls;
            }
        }
        grid.sync();
        // ---- S4: combine chunk partials -> Xa (b x dseg partition) ----
        {
            int b = bk >> 3, ds0 = (bk & 7) * 64;
            if (tid < 64) {
                float L = 0.f;
#pragma unroll
                for (int i = 0; i < NCH; i++) L += pl[b * NCH + i];
                float inv = __builtin_amdgcn_rcpf(L);
                int d = ds0 + tid;
                float s = 0.f;
#pragma unroll
                for (int i = 0; i < NCH; i++)
                    s += pacc[((size_t)(b * NCH + i)) * 512 + d];
                Xa[b * 512 + d] = s * inv;
            }
        }
        grid.sync();
        // ---- S5: z = zbuf + Xa@Waz, gates, state update ----
        // block owns u's {2bk,2bk+1} x 4 gate quadrants = 8 z-cols x 32 b
        {
            for (int idx = tid; idx < 16384; idx += 512)
                smem[(idx >> 9) * 513 + (idx & 511)] = Xa[idx];
            int u0 = bk * 2;
            for (int idx = tid; idx < 4096; idx += 512) {
                int rw = idx >> 9, d = idx & 511;
                int g = (rw >> 1) * 512 + u0 + (rw & 1);
                smem[16416 + rw * 513 + d] = Wazt[(size_t)g * 512 + d];
            }
            __syncthreads();
            int q = tid & 1, o = tid >> 1;
            int col = o >> 5, b = o & 31;
            const float* xrow = smem + b * 513;
            const float* wrow = smem + 16416 + col * 513;
            float acc = 0.f;
#pragma unroll 8
            for (int i = 0; i < 256; ++i) {
                int d = q * 256 + i;
                acc += xrow[d] * wrow[d];
            }
            acc += __shfl_xor(acc, 1, 64);
            if (q == 0) {
                int g = (col >> 1) * 512 + u0 + (col & 1);
                smem[20520 + col * 32 + b] = acc + zbuf[b * 2048 + g];
            }
            __syncthreads();
            if (tid < 64) {
                int bb = tid >> 1, uo = tid & 1;
                int u = u0 + uo;
                float zi = smem[20520 + (0 + uo) * 32 + bb];
                float zf = smem[20520 + (2 + uo) * 32 + bb];
                float zg = smem[20520 + (4 + uo) * 32 + bb];
                float zo = smem[20520 + (6 + uo) * 32 + bb];
                float ig = fast_sig(zi);
                float fg = fast_sig(zf);
                float gg = fast_tanh(zg);
                float og = fast_sig(zo);
                int idx = bb * 512 + u;
                float cn = fg * c[idx] + ig * gg;
                float hn = og * fast_tanh(cn);
                c[idx] = cn;
                h[idx] = hn;
                out[((size_t)bb * TDEC + t) * 512 + u] = hn;
            }
        }
        grid.sync();
    }
}

extern "C" void kernel_launch(void* const* d_in, const int* in_sizes, int n_in,
                              void* d_out, int out_size, void* d_ws, size_t ws_size,
                              hipStream_t stream) {
    const float* enc = (const float*)d_in[0];
    const float* dec = (const float*)d_in[1];
    const float* W1 = (const float*)d_in[2];
    const float* W2 = (const float*)d_in[3];
    const float* b2 = (const float*)d_in[4];
    const float* V = (const float*)d_in[5];
    const float* W3 = (const float*)d_in[6];
    const float* b3 = (const float*)d_in[7];
    const float* Wk = (const float*)d_in[8];
    const float* Wr = (const float*)d_in[9];
    const float* bias = (const float*)d_in[10];
    float* out = (float*)d_out;

    char* ws = (char*)d_ws;
    size_t o = 0;
    auto alloc = [&](size_t bytes) {
        void* p = ws + o;
        o += (bytes + 255) & ~(size_t)255;
        return p;
    };
    ushort_t* xW1h = (ushort_t*)alloc(67108864);        // [65536][512] bf16
    ushort_t* ench = (ushort_t*)alloc(67108864);        // [65536][512] bf16
    float* Zxf = (float*)alloc(33554432);               // [4096][2048] f32
    ushort_t* dech = (ushort_t*)alloc(4194304);         // [4096][512] bf16
    ushort_t* T1h = (ushort_t*)alloc(4194304);          // [4096][512] bf16
    ushort_t* W3h = (ushort_t*)alloc(1048576);          // [1024][512] bf16 (W3 as-is)
    ushort_t* W3at = (ushort_t*)alloc(524288);          // [512][512] bf16 (upper W3^T)
    ushort_t* Wkt = (ushort_t*)alloc(2097152);          // [2048][512] bf16 (Wk^T)
    float* W2t = (float*)alloc(1048576);                // [512][512] f32 (W2^T)
    float* Wrt = (float*)alloc(4194304);                // [2048][512] f32 (Wr^T)
    float* Wazt = (float*)alloc(4194304);               // [2048][512] f32 ((W3b@Wk)^T)
    float* bz = (float*)alloc(8192);                    // [2048]
    float* h = (float*)alloc(65536);                    // [32][512]
    float* c = (float*)alloc(65536);                    // [32][512] (contiguous after h)
    float* hW2 = (float*)alloc(65536);
    float* Xa = (float*)alloc(65536);
    float* zbuf = (float*)alloc(262144);                // [32][2048]
    float* pl = (float*)alloc(1024);
    float* pacc = (float*)alloc(524288);                // [32][8][512]

    hipMemsetAsync(h, 0, 131072, stream);  // h and c

    // one-time converts / transposes
    cvt_kernel<<<16384, 256, 0, stream>>>(enc, ench);
    cvt_kernel<<<1024, 256, 0, stream>>>(dec, dech);
    cvt_kernel<<<256, 256, 0, stream>>>(W3, W3h);
    tr_cvt_bf16_kernel<<<dim3(16, 16), 256, 0, stream>>>(W3, W3at, 512, 512);
    tr_cvt_bf16_kernel<<<dim3(64, 16), 256, 0, stream>>>(Wk, Wkt, 512, 2048);
    tr_f32_kernel<<<dim3(16, 16), 256, 0, stream>>>(W2, W2t, 512, 512);
    tr_f32_kernel<<<dim3(64, 16), 256, 0, stream>>>(Wr, Wrt, 512, 2048);
    bz_kernel<<<8, 256, 0, stream>>>(b3, Wk, bias, bz);
    // one-time GEMMs
    gemm_xw1_kernel<<<dim3(8, 1024), 256, 0, stream>>>(enc, W1, xW1h);   // fp32 math
    mfma_gemm_kernel<1><<<dim3(8, 64), 256, 0, stream>>>(dech, W3at, T1h, 4096, 512);
    mfma_gemm_kernel<0><<<dim3(32, 64), 256, 0, stream>>>(T1h, Wkt, Zxf, 4096, 2048);
    mfma_gemm_kernel<0><<<dim3(8, 32), 256, 0, stream>>>(Wkt, W3h + 512 * 512, Wazt, 2048, 512);

    // persistent decode loop (one cooperative dispatch, 4 grid syncs/step)
    void* args[] = {&xW1h, &ench, &Zxf, &bz, &W2t, &Wrt, &Wazt, &V, &b2,
                    &h, &c, &hW2, &zbuf, &pl, &pacc, &Xa, &out};
    hipLaunchCooperativeKernel((void*)step_kernel, dim3(256), dim3(512), args, 0, stream);
}

// Round 5
// 18866.628 us; speedup vs baseline: 1.2142x; 1.1564x over previous
//
#include <hip/hip_runtime.h>
#include <cstddef>
#include <cstdint>

#define B 32
#define TENC 2048
#define TDEC 128
#define NCH 8     // attn chunks per batch: 32 b x 8 ch = 256 blocks
#define TCH 256   // t per chunk (8 waves x 32)

typedef unsigned short ushort_t;
typedef __attribute__((ext_vector_type(8))) short short8;
typedef __attribute__((ext_vector_type(4))) float floatx4;

// ---------------- helpers ----------------
__device__ __forceinline__ uint16_t f2bf(float x) {
    uint32_t u = __float_as_uint(x);
    u += 0x7fffu + ((u >> 16) & 1u);  // RNE
    return (uint16_t)(u >> 16);
}
__device__ __forceinline__ void unpack8(uint4 v, float* f) {
    f[0] = __uint_as_float(v.x << 16); f[1] = __uint_as_float(v.x & 0xffff0000u);
    f[2] = __uint_as_float(v.y << 16); f[3] = __uint_as_float(v.y & 0xffff0000u);
    f[4] = __uint_as_float(v.z << 16); f[5] = __uint_as_float(v.z & 0xffff0000u);
    f[6] = __uint_as_float(v.w << 16); f[7] = __uint_as_float(v.w & 0xffff0000u);
}
__device__ __forceinline__ float fast_tanh(float x) {
    float e = __expf(2.f * x);
    return 1.f - 2.f * __builtin_amdgcn_rcpf(e + 1.f);
}
__device__ __forceinline__ float fast_sig(float x) {
    return __builtin_amdgcn_rcpf(1.f + __expf(-x));
}

// ---- custom two-level grid barrier (bar[0]=gen, bar[64]=root, bar[128+g*64]=group g) ----
__device__ __forceinline__ void gridbar(unsigned* bar) {
    __syncthreads();
    if (threadIdx.x == 0) {
        unsigned g = __hip_atomic_load(bar, __ATOMIC_RELAXED, __HIP_MEMORY_SCOPE_AGENT);
        __threadfence();  // release: make this block's writes device-visible
        unsigned grp = blockIdx.x >> 5;
        unsigned* gcnt = bar + 128 + grp * 64;
        unsigned old = __hip_atomic_fetch_add(gcnt, 1u, __ATOMIC_ACQ_REL, __HIP_MEMORY_SCOPE_AGENT);
        if (old == 31u) {  // last of this 32-block group
            __hip_atomic_store(gcnt, 0u, __ATOMIC_RELAXED, __HIP_MEMORY_SCOPE_AGENT);
            unsigned rold =
                __hip_atomic_fetch_add(bar + 64, 1u, __ATOMIC_ACQ_REL, __HIP_MEMORY_SCOPE_AGENT);
            if (rold == 7u) {  // last group: flip generation
                __hip_atomic_store(bar + 64, 0u, __ATOMIC_RELAXED, __HIP_MEMORY_SCOPE_AGENT);
                __hip_atomic_store(bar, g + 1u, __ATOMIC_RELEASE, __HIP_MEMORY_SCOPE_AGENT);
            } else {
                while (__hip_atomic_load(bar, __ATOMIC_ACQUIRE, __HIP_MEMORY_SCOPE_AGENT) == g)
                    __builtin_amdgcn_s_sleep(1);
            }
        } else {
            while (__hip_atomic_load(bar, __ATOMIC_ACQUIRE, __HIP_MEMORY_SCOPE_AGENT) == g)
                __builtin_amdgcn_s_sleep(1);
        }
    }
    __syncthreads();
}

// ---------------- f32 -> bf16 bulk convert (count = grid*2048) ----------------
__global__ void cvt_kernel(const float* __restrict__ in, ushort_t* __restrict__ out) {
    int i = blockIdx.x * 256 + threadIdx.x;  // 8 elements each
    const float4* ip = (const float4*)in;
    float4 a = ip[2 * i], b = ip[2 * i + 1];
    uint4 o;
    o.x = (uint32_t)f2bf(a.x) | ((uint32_t)f2bf(a.y) << 16);
    o.y = (uint32_t)f2bf(a.z) | ((uint32_t)f2bf(a.w) << 16);
    o.z = (uint32_t)f2bf(b.x) | ((uint32_t)f2bf(b.y) << 16);
    o.w = (uint32_t)f2bf(b.z) | ((uint32_t)f2bf(b.w) << 16);
    ((uint4*)out)[i] = o;
}

// ---------------- transpose (+ optional cvt): out[c*R+r] = in[r*C+c] ----------------
__global__ void tr_cvt_bf16_kernel(const float* __restrict__ in, ushort_t* __restrict__ out,
                                   int R, int C) {
    __shared__ float tile[32][33];
    int r0 = blockIdx.y * 32, c0 = blockIdx.x * 32;
    int tx = threadIdx.x & 31, ty = threadIdx.x >> 5;
#pragma unroll
    for (int i = 0; i < 4; i++) {
        int r = ty + i * 8;
        tile[r][tx] = in[(size_t)(r0 + r) * C + c0 + tx];
    }
    __syncthreads();
#pragma unroll
    for (int i = 0; i < 4; i++) {
        int rr = ty + i * 8;
        out[(size_t)(c0 + rr) * R + r0 + tx] = f2bf(tile[tx][rr]);
    }
}
__global__ void tr_f32_kernel(const float* __restrict__ in, float* __restrict__ out,
                              int R, int C) {
    __shared__ float tile[32][33];
    int r0 = blockIdx.y * 32, c0 = blockIdx.x * 32;
    int tx = threadIdx.x & 31, ty = threadIdx.x >> 5;
#pragma unroll
    for (int i = 0; i < 4; i++) {
        int r = ty + i * 8;
        tile[r][tx] = in[(size_t)(r0 + r) * C + c0 + tx];
    }
    __syncthreads();
#pragma unroll
    for (int i = 0; i < 4; i++) {
        int rr = ty + i * 8;
        out[(size_t)(c0 + rr) * R + r0 + tx] = tile[tx][rr];
    }
}

// ---------------- bz[g] = bias[g] + b3 @ Wk[:,g] ----------------
__global__ void bz_kernel(const float* __restrict__ b3, const float* __restrict__ Wk,
                          const float* __restrict__ bias, float* __restrict__ bz) {
    int g = blockIdx.x * 256 + threadIdx.x;
    float s = bias[g];
#pragma unroll 8
    for (int u = 0; u < 512; u++) s += b3[u] * Wk[(size_t)u * 2048 + g];
    bz[g] = s;
}

// -------- one-time: xW1 = enc @ W1, fp32 math (single bf16 store-rounding) --------
__global__ void gemm_xw1_kernel(const float* __restrict__ A, const float* __restrict__ Bm,
                                ushort_t* __restrict__ C) {
    __shared__ float As[16][68];
    __shared__ float Bs[16][68];
    int bm = blockIdx.y * 64, bn = blockIdx.x * 64;
    int tx = threadIdx.x & 15, ty = threadIdx.x >> 4;
    float acc[4][4] = {};
    for (int k0 = 0; k0 < 512; k0 += 16) {
#pragma unroll
        for (int i = 0; i < 4; i++) {
            int idx = threadIdx.x + 256 * i;
            int r = idx >> 4, kk = idx & 15;
            As[kk][r] = A[(size_t)(bm + r) * 512 + k0 + kk];
            int cc = idx & 63, kb = idx >> 6;
            Bs[kb][cc] = Bm[(size_t)(k0 + kb) * 512 + bn + cc];
        }
        __syncthreads();
#pragma unroll
        for (int kk = 0; kk < 16; kk++) {
            float4 av = *(const float4*)&As[kk][ty * 4];
            float4 bv = *(const float4*)&Bs[kk][tx * 4];
            float a[4] = {av.x, av.y, av.z, av.w};
            float b[4] = {bv.x, bv.y, bv.z, bv.w};
#pragma unroll
            for (int i = 0; i < 4; i++)
#pragma unroll
                for (int j = 0; j < 4; j++) acc[i][j] += a[i] * b[j];
        }
        __syncthreads();
    }
#pragma unroll
    for (int i = 0; i < 4; i++) {
        uint2 o;
        o.x = (uint32_t)f2bf(acc[i][0]) | ((uint32_t)f2bf(acc[i][1]) << 16);
        o.y = (uint32_t)f2bf(acc[i][2]) | ((uint32_t)f2bf(acc[i][3]) << 16);
        *(uint2*)(C + (size_t)(bm + ty * 4 + i) * 512 + bn + tx * 4) = o;
    }
}

// ---------------- MFMA bf16 GEMM: C[M,N] = A[M,512] x Bt[N,512]^T ----------------
template <int BF16OUT>
__global__ void mfma_gemm_kernel(const ushort_t* __restrict__ A, const ushort_t* __restrict__ Bt,
                                 void* __restrict__ C, int M, int N) {
    int tid = threadIdx.x, wave = tid >> 6, lane = tid & 63;
    int wy = wave & 1, wx = wave >> 1;
    int m0 = blockIdx.y * 64 + wy * 32;
    int n0 = blockIdx.x * 64 + wx * 32;
    int lr = lane & 15, quad = lane >> 4;
    floatx4 a00 = {0.f, 0.f, 0.f, 0.f}, a01 = a00, a10 = a00, a11 = a00;
    const short8* Ap0 = (const short8*)(A + (size_t)(m0 + lr) * 512 + quad * 8);
    const short8* Ap1 = (const short8*)(A + (size_t)(m0 + 16 + lr) * 512 + quad * 8);
    const short8* Bp0 = (const short8*)(Bt + (size_t)(n0 + lr) * 512 + quad * 8);
    const short8* Bp1 = (const short8*)(Bt + (size_t)(n0 + 16 + lr) * 512 + quad * 8);
#pragma unroll 4
    for (int k = 0; k < 16; k++) {
        short8 av0 = Ap0[k * 4], av1 = Ap1[k * 4];
        short8 bv0 = Bp0[k * 4], bv1 = Bp1[k * 4];
        a00 = __builtin_amdgcn_mfma_f32_16x16x32_bf16(av0, bv0, a00, 0, 0, 0);
        a01 = __builtin_amdgcn_mfma_f32_16x16x32_bf16(av0, bv1, a01, 0, 0, 0);
        a10 = __builtin_amdgcn_mfma_f32_16x16x32_bf16(av1, bv0, a10, 0, 0, 0);
        a11 = __builtin_amdgcn_mfma_f32_16x16x32_bf16(av1, bv1, a11, 0, 0, 0);
    }
    int rb = quad * 4;
    if (BF16OUT) {
        ushort_t* Cp = (ushort_t*)C;
#pragma unroll
        for (int r = 0; r < 4; r++) {
            Cp[(size_t)(m0 + rb + r) * N + n0 + lr] = f2bf(a00[r]);
            Cp[(size_t)(m0 + rb + r) * N + n0 + 16 + lr] = f2bf(a01[r]);
            Cp[(size_t)(m0 + 16 + rb + r) * N + n0 + lr] = f2bf(a10[r]);
            Cp[(size_t)(m0 + 16 + rb + r) * N + n0 + 16 + lr] = f2bf(a11[r]);
        }
    } else {
        float* Cp = (float*)C;
#pragma unroll
        for (int r = 0; r < 4; r++) {
            Cp[(size_t)(m0 + rb + r) * N + n0 + lr] = a00[r];
            Cp[(size_t)(m0 + rb + r) * N + n0 + 16 + lr] = a01[r];
            Cp[(size_t)(m0 + 16 + rb + r) * N + n0 + lr] = a10[r];
            Cp[(size_t)(m0 + 16 + rb + r) * N + n0 + 16 + lr] = a11[r];
        }
    }
}

// =================== persistent cooperative decode kernel ===================
// 256 blocks x 512 threads (8 waves/CU). 4 custom grid barriers per step.
__global__ __launch_bounds__(512, 2) void step_kernel(
    const ushort_t* __restrict__ xW1h, const ushort_t* __restrict__ ench,
    const float* __restrict__ Zxf, const float* __restrict__ bz,
    const float* __restrict__ W2t, const float* __restrict__ Wrt,
    const float* __restrict__ Wazt, const float* __restrict__ Vv,
    const float* __restrict__ b2,
    float* __restrict__ h, float* __restrict__ c, float* __restrict__ hW2,
    float* __restrict__ zbuf, float* __restrict__ pl,
    float* __restrict__ pacc, float* __restrict__ Xa, float* __restrict__ out,
    unsigned* bar) {
    int bk = blockIdx.x, tid = threadIdx.x;
    int wave = tid >> 6, lane = tid & 63;
    __shared__ float smem[21560];

    // attention-phase per-lane constants (V is loop-invariant)
    float vs[8];
    {
        const float4* vp = (const float4*)(Vv + lane * 8);
        float4 v0 = vp[0], v1 = vp[1];
        vs[0] = v0.x; vs[1] = v0.y; vs[2] = v0.z; vs[3] = v0.w;
        vs[4] = v1.x; vs[5] = v1.y; vs[6] = v1.z; vs[7] = v1.w;
    }

    for (int t = 0; t < TDEC; ++t) {
        // ---- S2: hW2 = h@W2t + b2 ; zbuf = h@Wrt + Zx[b,t] + bz ----
        // this block owns cols n0..n0+9 of concat [W2t | Wrt] (2560 cols / 256 blocks)
        {
            for (int idx = tid; idx < 16384; idx += 512)
                smem[(idx >> 9) * 513 + (idx & 511)] = h[idx];
            int n0 = bk * 10;
            for (int idx = tid; idx < 5120; idx += 512) {
                int cc = idx >> 9, d = idx & 511;
                int n = n0 + cc;
                const float* src = (n < 512) ? (W2t + (size_t)n * 512)
                                             : (Wrt + (size_t)(n - 512) * 512);
                smem[16416 + cc * 513 + d] = src[d];
            }
            __syncthreads();
            int q = tid & 3, slot = tid >> 2;
#pragma unroll
            for (int r = 0; r < 3; ++r) {
                int o = r * 128 + slot;
                bool valid = (o < 320);
                int cc = o >> 5, b = o & 31;
                if (cc > 9) cc = 9;
                const float* hrow = smem + b * 513;
                const float* wrow = smem + 16416 + cc * 513;
                float acc = 0.f;
#pragma unroll 8
                for (int i = 0; i < 128; ++i) {
                    int d = q + 4 * i;
                    acc += hrow[d] * wrow[d];
                }
                acc += __shfl_xor(acc, 1, 64);
                acc += __shfl_xor(acc, 2, 64);
                if (q == 0 && valid) {
                    int n = n0 + cc;
                    if (n < 512) {
                        hW2[b * 512 + n] = acc + b2[n];
                    } else {
                        int g = n - 512;
                        zbuf[b * 2048 + g] =
                            acc + Zxf[((size_t)(b * 128 + t)) * 2048 + g] + bz[g];
                    }
                }
            }
        }
        gridbar(bar);
        // ---- S3: fixed-base softmax attention partials (depth-4 prefetch) ----
        {
            int b = bk >> 3, ch = bk & 7;
            float hs[8];
            {
                const float4* hp = (const float4*)(hW2 + b * 512 + lane * 8);
                float4 h0 = hp[0], h1 = hp[1];
                hs[0] = h0.x; hs[1] = h0.y; hs[2] = h0.z; hs[3] = h0.w;
                hs[4] = h1.x; hs[5] = h1.y; hs[6] = h1.z; hs[7] = h1.w;
            }
            int t0 = ch * TCH + wave * 32;
            const uint4* xr = (const uint4*)xW1h + ((size_t)b * TENC + t0) * 64 + lane;
            const uint4* er = (const uint4*)ench + ((size_t)b * TENC + t0) * 64 + lane;
            float l = 0.f;
            float acc[8] = {0.f, 0.f, 0.f, 0.f, 0.f, 0.f, 0.f, 0.f};

            auto body = [&](uint4 xv, uint4 ev) {
                float xf[8], ef[8];
                unpack8(xv, xf);
                float s = 0.f;
#pragma unroll
                for (int j = 0; j < 8; j++) s += fast_tanh(xf[j] + hs[j]) * vs[j];
#pragma unroll
                for (int off = 32; off >= 1; off >>= 1) s += __shfl_xor(s, off, 64);
                float p = __expf(s);  // |s| <= ~21 -> safe in fp32 without max
                l += p;
                unpack8(ev, ef);
#pragma unroll
                for (int j = 0; j < 8; j++) acc[j] += p * ef[j];
            };

            uint4 xb[4], eb[4];
#pragma unroll
            for (int i = 0; i < 4; i++) {
                xb[i] = xr[(size_t)i * 64];
                eb[i] = er[(size_t)i * 64];
            }
#pragma unroll 4
            for (int tt = 0; tt < 28; ++tt) {
                int sl = tt & 3;
                uint4 xv = xb[sl], ev = eb[sl];
                xb[sl] = xr[(size_t)(tt + 4) * 64];
                eb[sl] = er[(size_t)(tt + 4) * 64];
                body(xv, ev);
            }
#pragma unroll
            for (int tt = 28; tt < 32; ++tt) body(xb[tt & 3], eb[tt & 3]);

            // block combine: plain sums across 8 waves
            float* slv = smem;            // [8]
            float* sacc = smem + 16;      // [8][512]
            if (lane == 0) slv[wave] = l;
            float4* sa = (float4*)(sacc + wave * 512 + lane * 8);
            sa[0] = make_float4(acc[0], acc[1], acc[2], acc[3]);
            sa[1] = make_float4(acc[4], acc[5], acc[6], acc[7]);
            __syncthreads();
            float sd = 0.f;
#pragma unroll
            for (int w = 0; w < 8; w++) sd += sacc[w * 512 + tid];
            size_t po = ((size_t)(b * NCH + ch)) * 512;
            pacc[po + tid] = sd;
            if (tid == 0) {
                float ls = 0.f;
#pragma unroll
                for (int w = 0; w < 8; w++) ls += slv[w];
                pl[b * NCH + ch] = ls;
            }
        }
        gridbar(bar);
        // ---- S4: combine chunk partials -> Xa (b x dseg partition) ----
        {
            int b = bk >> 3, ds0 = (bk & 7) * 64;
            if (tid < 64) {
                float L = 0.f;
#pragma unroll
                for (int i = 0; i < NCH; i++) L += pl[b * NCH + i];
                float inv = __builtin_amdgcn_rcpf(L);
                int d = ds0 + tid;
                float s = 0.f;
#pragma unroll
                for (int i = 0; i < NCH; i++)
                    s += pacc[((size_t)(b * NCH + i)) * 512 + d];
                Xa[b * 512 + d] = s * inv;
            }
        }
        gridbar(bar);
        // ---- S5: z = zbuf + Xa@Waz, gates, state update ----
        // block owns u's {2bk,2bk+1} x 4 gate quadrants = 8 z-cols x 32 b
        {
            for (int idx = tid; idx < 16384; idx += 512)
                smem[(idx >> 9) * 513 + (idx & 511)] = Xa[idx];
            int u0 = bk * 2;
            for (int idx = tid; idx < 4096; idx += 512) {
                int rw = idx >> 9, d = idx & 511;
                int g = (rw >> 1) * 512 + u0 + (rw & 1);
                smem[16416 + rw * 513 + d] = Wazt[(size_t)g * 512 + d];
            }
            __syncthreads();
            int q = tid & 1, o = tid >> 1;
            int col = o >> 5, b = o & 31;
            const float* xrow = smem + b * 513;
            const float* wrow = smem + 16416 + col * 513;
            float acc = 0.f;
#pragma unroll 8
            for (int i = 0; i < 256; ++i) {
                int d = q * 256 + i;
                acc += xrow[d] * wrow[d];
            }
            acc += __shfl_xor(acc, 1, 64);
            if (q == 0) {
                int g = (col >> 1) * 512 + u0 + (col & 1);
                smem[20520 + col * 32 + b] = acc + zbuf[b * 2048 + g];
            }
            __syncthreads();
            if (tid < 64) {
                int bb = tid >> 1, uo = tid & 1;
                int u = u0 + uo;
                float zi = smem[20520 + (0 + uo) * 32 + bb];
                float zf = smem[20520 + (2 + uo) * 32 + bb];
                float zg = smem[20520 + (4 + uo) * 32 + bb];
                float zo = smem[20520 + (6 + uo) * 32 + bb];
                float ig = fast_sig(zi);
                float fg = fast_sig(zf);
                float gg = fast_tanh(zg);
                float og = fast_sig(zo);
                int idx = bb * 512 + u;
                float cn = fg * c[idx] + ig * gg;
                float hn = og * fast_tanh(cn);
                c[idx] = cn;
                h[idx] = hn;
                out[((size_t)bb * TDEC + t) * 512 + u] = hn;
            }
        }
        if (t < TDEC - 1) gridbar(bar);
    }
}

extern "C" void kernel_launch(void* const* d_in, const int* in_sizes, int n_in,
                              void* d_out, int out_size, void* d_ws, size_t ws_size,
                              hipStream_t stream) {
    const float* enc = (const float*)d_in[0];
    const float* dec = (const float*)d_in[1];
    const float* W1 = (const float*)d_in[2];
    const float* W2 = (const float*)d_in[3];
    const float* b2 = (const float*)d_in[4];
    const float* V = (const float*)d_in[5];
    const float* W3 = (const float*)d_in[6];
    const float* b3 = (const float*)d_in[7];
    const float* Wk = (const float*)d_in[8];
    const float* Wr = (const float*)d_in[9];
    const float* bias = (const float*)d_in[10];
    float* out = (float*)d_out;

    char* ws = (char*)d_ws;
    size_t o = 0;
    auto alloc = [&](size_t bytes) {
        void* p = ws + o;
        o += (bytes + 255) & ~(size_t)255;
        return p;
    };
    ushort_t* xW1h = (ushort_t*)alloc(67108864);        // [65536][512] bf16
    ushort_t* ench = (ushort_t*)alloc(67108864);        // [65536][512] bf16
    float* Zxf = (float*)alloc(33554432);               // [4096][2048] f32
    ushort_t* dech = (ushort_t*)alloc(4194304);         // [4096][512] bf16
    ushort_t* T1h = (ushort_t*)alloc(4194304);          // [4096][512] bf16
    ushort_t* W3h = (ushort_t*)alloc(1048576);          // [1024][512] bf16 (W3 as-is)
    ushort_t* W3at = (ushort_t*)alloc(524288);          // [512][512] bf16 (upper W3^T)
    ushort_t* Wkt = (ushort_t*)alloc(2097152);          // [2048][512] bf16 (Wk^T)
    float* W2t = (float*)alloc(1048576);                // [512][512] f32 (W2^T)
    float* Wrt = (float*)alloc(4194304);                // [2048][512] f32 (Wr^T)
    float* Wazt = (float*)alloc(4194304);               // [2048][512] f32 ((W3b@Wk)^T)
    float* bz = (float*)alloc(8192);                    // [2048]
    float* h = (float*)alloc(65536);                    // [32][512]
    float* c = (float*)alloc(65536);                    // [32][512] (contiguous after h)
    float* hW2 = (float*)alloc(65536);
    float* Xa = (float*)alloc(65536);
    float* zbuf = (float*)alloc(262144);                // [32][2048]
    float* pl = (float*)alloc(1024);
    float* pacc = (float*)alloc(524288);                // [32][8][512]
    unsigned* bar = (unsigned*)alloc(4096);             // barrier state (must be zeroed)

    hipMemsetAsync(h, 0, 131072, stream);  // h and c
    hipMemsetAsync(bar, 0, 4096, stream);  // barrier counters + generation

    // one-time converts / transposes
    cvt_kernel<<<16384, 256, 0, stream>>>(enc, ench);
    cvt_kernel<<<1024, 256, 0, stream>>>(dec, dech);
    cvt_kernel<<<256, 256, 0, stream>>>(W3, W3h);
    tr_cvt_bf16_kernel<<<dim3(16, 16), 256, 0, stream>>>(W3, W3at, 512, 512);
    tr_cvt_bf16_kernel<<<dim3(64, 16), 256, 0, stream>>>(Wk, Wkt, 512, 2048);
    tr_f32_kernel<<<dim3(16, 16), 256, 0, stream>>>(W2, W2t, 512, 512);
    tr_f32_kernel<<<dim3(64, 16), 256, 0, stream>>>(Wr, Wrt, 512, 2048);
    bz_kernel<<<8, 256, 0, stream>>>(b3, Wk, bias, bz);
    // one-time GEMMs
    gemm_xw1_kernel<<<dim3(8, 1024), 256, 0, stream>>>(enc, W1, xW1h);   // fp32 math
    mfma_gemm_kernel<1><<<dim3(8, 64), 256, 0, stream>>>(dech, W3at, T1h, 4096, 512);
    mfma_gemm_kernel<0><<<dim3(32, 64), 256, 0, stream>>>(T1h, Wkt, Zxf, 4096, 2048);
    mfma_gemm_kernel<0><<<dim3(8, 32), 256, 0, stream>>>(Wkt, W3h + 512 * 512, Wazt, 2048, 512);

    // persistent decode loop (one cooperative dispatch for co-residency; custom barriers inside)
    void* args[] = {&xW1h, &ench, &Zxf, &bz, &W2t, &Wrt, &Wazt, &V, &b2,
                    &h, &c, &hW2, &zbuf, &pl, &pacc, &Xa, &out, &bar};
    hipLaunchCooperativeKernel((void*)step_kernel, dim3(256), dim3(512), args, 0, stream);
}